// Round 13
// baseline (533.857 us; speedup 1.0000x reference)
//
#include <hip/hip_runtime.h>

#define DEVI __device__ __forceinline__

namespace {

constexpr int Nn = 50000;   // nodes
constexpr int Ne = 800000;  // edges
constexpr int Fd = 128;     // feature dim
constexpr int Hd = 256;     // hidden
constexpr int Cd = 40;      // classes
constexpr int NB = (Nn + 255) / 256;  // 196 scan blocks

typedef __attribute__((ext_vector_type(8))) short s16x8;   // 8 bf16 MFMA frag
typedef __attribute__((ext_vector_type(8))) unsigned short u16x8;
typedef __attribute__((ext_vector_type(4))) float f32x4;
typedef __attribute__((ext_vector_type(4))) unsigned int u32x4;

DEVI unsigned short f2bf(float f) {
  unsigned int u = __builtin_bit_cast(unsigned int, f);
  u += 0x7fffu + ((u >> 16) & 1u);   // RNE
  return (unsigned short)(u >> 16);
}
DEVI float bf2f(unsigned short s) {
  return __builtin_bit_cast(float, ((unsigned int)s) << 16);
}
// 2x f32 -> packed bf16x2 (RNE), one VALU op (gfx950)
DEVI unsigned cvtpk(float lo, float hi) {
  unsigned r;
  asm("v_cvt_pk_bf16_f32 %0, %1, %2" : "=v"(r) : "v"(lo), "v"(hi));
  return r;
}

// Direct HBM->LDS 16B/lane load: M0 = wave-uniform LDS byte base,
// HW writes LDS at M0 + lane*16. gptr is per-lane. (validated R5)
DEVI void gld_lds16(const void* gptr, void* lds_base) {
  const unsigned m0v =
      (unsigned)__builtin_amdgcn_readfirstlane((unsigned)(uintptr_t)lds_base);
  asm volatile("s_mov_b32 m0, %0\n\t"
               "global_load_lds_dwordx4 %1, off"
               :: "s"(m0v), "v"(gptr) : "memory");
}

// ---------------- fused prep: 7 weight transposes (PRE-SWIZZLED) + cnt zero ---
DEVI void wt_one(const float* __restrict__ W, unsigned short* __restrict__ Wt,
                 int idx, int K, int H, const float* __restrict__ ow) {
  int c = idx / K, k = idx - c * K;
  int kt = k >> 6, c16 = (k >> 3) & 7, j = k & 7;
  int ksrc = (kt << 6) | ((c16 ^ (c & 7)) << 3) | j;
  float v = (c < H) ? W[(size_t)ksrc * H + c] : 0.0f;
  if (ow) v *= ow[(ksrc >> 7) & 1];
  Wt[idx] = f2bf(v);
}

constexpr int WTO0 = 0;
constexpr int WTO1 = WTO0 + 256 * 128;  // convW0
constexpr int WTO2 = WTO1 + 256 * 512;  // convW1
constexpr int WTO3 = WTO2 + 256 * 512;  // convW2
constexpr int WTO4 = WTO3 + 256 * 128;  // linW0
constexpr int WTO5 = WTO4 + 256 * 256;  // linW1 (ow)
constexpr int WTO6 = WTO5 + 256 * 512;  // linW2 (ow)
constexpr int WTO7 = WTO6 + 64 * 512;   // clsW
constexpr int PREPTOT = WTO7 + Nn;

__global__ __launch_bounds__(256) void k_prep(
    const float* W0, const float* W1, const float* W2, const float* W3,
    const float* W4, const float* W5, const float* W6, const float* ow,
    unsigned short* T0, unsigned short* T1, unsigned short* T2, unsigned short* T3,
    unsigned short* T4, unsigned short* T5, unsigned short* T6, int* cnt) {
  int idx = blockIdx.x * 256 + threadIdx.x;
  if (idx >= PREPTOT) return;
  if (idx < WTO1)      wt_one(W0, T0, idx - WTO0, 128, 256, nullptr);
  else if (idx < WTO2) wt_one(W1, T1, idx - WTO1, 512, 256, nullptr);
  else if (idx < WTO3) wt_one(W2, T2, idx - WTO2, 512, 256, nullptr);
  else if (idx < WTO4) wt_one(W3, T3, idx - WTO3, 128, 256, nullptr);
  else if (idx < WTO5) wt_one(W4, T4, idx - WTO4, 256, 256, ow);
  else if (idx < WTO6) wt_one(W5, T5, idx - WTO5, 512, 256, ow);
  else if (idx < WTO7) wt_one(W6, T6, idx - WTO6, 512, 40, nullptr);
  else cnt[idx - WTO7] = 0;
}

// ---------------- CSR build ----------------
__global__ void k_count(const int* __restrict__ dst, int* __restrict__ cnt) {
  int e = blockIdx.x * 256 + threadIdx.x;
  if (e < Ne) atomicAdd(&cnt[dst[e]], 1);
}

__global__ __launch_bounds__(256) void k_partial(const int* __restrict__ cnt,
                                                 int* __restrict__ partial) {
  __shared__ int red[256];
  const int t = threadIdx.x;
  const int i = blockIdx.x * 256 + t;
  red[t] = (i < Nn) ? cnt[i] + 1 : 0;
  __syncthreads();
#pragma unroll
  for (int off = 128; off; off >>= 1) {
    if (t < off) red[t] += red[t + off];
    __syncthreads();
  }
  if (t == 0) partial[blockIdx.x] = red[0];
}

__global__ __launch_bounds__(256) void k_scan_small(const int* __restrict__ partial,
                                                    int* __restrict__ poffs,
                                                    int* __restrict__ rowptr) {
  __shared__ int s[256];
  const int t = threadIdx.x;
  const int v = (t < NB) ? partial[t] : 0;
  s[t] = v;
  __syncthreads();
#pragma unroll
  for (int off = 1; off < 256; off <<= 1) {
    int add = (t >= off) ? s[t - off] : 0;
    __syncthreads();
    s[t] += add;
    __syncthreads();
  }
  if (t < NB) poffs[t] = s[t] - v;        // exclusive
  if (t == NB - 1) rowptr[Nn] = s[t];     // total = Ne + Nn
}

__global__ __launch_bounds__(256) void k_rowptr(const int* __restrict__ cnt,
                                                const int* __restrict__ poffs,
                                                int* __restrict__ rowptr,
                                                int* __restrict__ cursor,
                                                float* __restrict__ dinv) {
  __shared__ int s[256];
  const int t = threadIdx.x;
  const int i = blockIdx.x * 256 + t;
  const int c = (i < Nn) ? cnt[i] + 1 : 0;
  s[t] = c;
  __syncthreads();
#pragma unroll
  for (int off = 1; off < 256; off <<= 1) {
    int add = (t >= off) ? s[t - off] : 0;
    __syncthreads();
    s[t] += add;
    __syncthreads();
  }
  if (i < Nn) {
    const int excl = s[t] - c + poffs[blockIdx.x];
    rowptr[i] = excl;
    cursor[i] = excl;
    dinv[i] = rsqrtf((float)c);
  }
}

__global__ void k_fill(const int* __restrict__ src, const int* __restrict__ dst,
                       const float* __restrict__ dinv, int* __restrict__ cursor,
                       int* __restrict__ csrs, float* __restrict__ csrn) {
  int e = blockIdx.x * 256 + threadIdx.x;
  if (e < Ne) {
    int s = src[e], d = dst[e];
    int pos = atomicAdd(&cursor[d], 1);
    csrs[pos] = s;
    csrn[pos] = dinv[s] * dinv[d];
  } else if (e < Ne + Nn) {
    int d = e - Ne;  // self loop
    int pos = atomicAdd(&cursor[d], 1);
    csrs[pos] = d;
    float v = dinv[d];
    csrn[pos] = v * v;
  }
}

// ---------------- fused MODE1 GEMM (4 roles): depth-3 A prefetch --------------
// BM=64, BN=256, 4 waves (wc=wid). LDS = A dbuf 2x8K + B single 32K = 48 KB.
// role = blockIdx.x & 3 (roles interleaved -> heterogeneous co-residency).
// B wave-private: readB->regs, lgkm0, overwrite. A: f32 loads depth-3 in named
// reg sets ArA/ArB/ArC (slot = kt%3). Top-of-step wait N retires exactly B(t):
// N = 4*[t+1<nkt] + 4*[t+2<nkt]. writeA reg-deps auto-waited by compiler.
struct GRole {
  const float* A;
  const unsigned short* Wt;
  const float* bias;
  unsigned short* C;
  int K;
  int ldc;
  int relu;
};

__global__ __launch_bounds__(256) void k_gemm4(GRole R0, GRole R1, GRole R2, GRole R3) {
  const int role = blockIdx.x & 3;
  const GRole R = (role == 0) ? R0 : (role == 1) ? R1 : (role == 2) ? R2 : R3;
  __shared__ char smem[49152];
  short* lA0 = (short*)smem;             // 8 KB
  short* lA1 = (short*)(smem + 8192);    // 8 KB
  short* lB  = (short*)(smem + 16384);   // 32 KB single, wave-private slices
  const int tid = threadIdx.x;
  const int lane = tid & 63;
  const int wid = tid >> 6;
  const int wc = wid;                 // wr = 0 (waves split cols)
  const int row0 = (blockIdx.x >> 2) * 64;
  const size_t NnF = (size_t)Nn * Fd;

  f32x4 acc[4][4];
#pragma unroll
  for (int i = 0; i < 4; ++i)
#pragma unroll
    for (int j = 0; j < 4; ++j) acc[i][j] = (f32x4)0.0f;

  auto issueA = [&](int kt, f32x4 (&A4)[2][2]) {
    const int k0 = kt * 64;
    const int c = k0 >> 7;
    const int f0 = k0 & 127;
#pragma unroll
    for (int i = 0; i < 2; ++i) {
      const int v = tid * 2 + i;
      const int row = v >> 3, c16 = v & 7;
      const int grow = row0 + row;
      const bool rv = grow < Nn;
      const float* p = R.A + (size_t)c * NnF + (size_t)grow * Fd + f0 + c16 * 8;
      A4[i][0] = rv ? *(const f32x4*)p : (f32x4)0.0f;
      A4[i][1] = rv ? *(const f32x4*)(p + 4) : (f32x4)0.0f;
    }
  };
  auto writeA = [&](f32x4 (&A4)[2][2], short* lAb) {
#pragma unroll
    for (int i = 0; i < 2; ++i) {
      const int v = tid * 2 + i;
      const int row = v >> 3, c16 = v & 7;
      u32x4 val;
      val.x = cvtpk(A4[i][0][0], A4[i][0][1]);
      val.y = cvtpk(A4[i][0][2], A4[i][0][3]);
      val.z = cvtpk(A4[i][1][0], A4[i][1][1]);
      val.w = cvtpk(A4[i][1][2], A4[i][1][3]);
      int byte = row * 128 + c16 * 16;
      byte ^= (row & 7) << 4;
      *(u32x4*)((char*)lAb + byte) = val;
    }
  };
  auto stageB = [&](int kt) {
    const int k0 = kt * 64;
#pragma unroll
    for (int i = 0; i < 8; ++i) {
      const int iss = wid * 8 + i;
      const int col = iss * 8 + (lane >> 3);
      gld_lds16(R.Wt + (size_t)col * R.K + k0 + (lane & 7) * 8, lB + iss * 512);
    }
  };
  auto readB = [&](s16x8 (&bv)[2][4]) {
#pragma unroll
    for (int kk = 0; kk < 2; ++kk)
#pragma unroll
      for (int ni = 0; ni < 4; ++ni) {
        int c = wc * 64 + ni * 16 + (lane & 15);
        int byte = c * 128 + kk * 64 + (lane >> 4) * 16;
        byte ^= (c & 7) << 4;
        bv[kk][ni] = *(const s16x8*)((const char*)lB + byte);
      }
  };
  auto mfma = [&](const short* lAb, s16x8 (&bv)[2][4]) {
#pragma unroll
    for (int kk = 0; kk < 2; ++kk) {
      s16x8 af[4];
#pragma unroll
      for (int mi = 0; mi < 4; ++mi) {
        int r = mi * 16 + (lane & 15);
        int byte = r * 128 + kk * 64 + (lane >> 4) * 16;
        byte ^= (r & 7) << 4;
        af[mi] = *(const s16x8*)((const char*)lAb + byte);
      }
#pragma unroll
      for (int mi = 0; mi < 4; ++mi)
#pragma unroll
        for (int ni = 0; ni < 4; ++ni)
          acc[mi][ni] = __builtin_amdgcn_mfma_f32_16x16x32_bf16(af[mi], bv[kk][ni], acc[mi][ni], 0, 0, 0);
    }
  };

  const int nkt = R.K >> 6;   // 2 / 2 / 4 / 8
  f32x4 ArA[2][2], ArB[2][2], ArC[2][2];   // slot = kt % 3 (named, rule #20)
  issueA(0, ArA);                    // slot 0
  stageB(0);                         // B(0)*8 in flight
  issueA(1, ArB);                    // slot 1
  if (nkt > 2) issueA(2, ArC);       // slot 2
  writeA(ArA, lA0);                  // implicit wait on A(0) regs
  asm volatile("s_waitcnt lgkmcnt(0)" ::: "memory");
  __builtin_amdgcn_s_barrier();
  for (int kt = 0; kt < nkt; ++kt) {
    // retire B(kt); keep A(kt+1), A(kt+2) flying
    const int nwait = ((kt + 1 < nkt) ? 4 : 0) + ((kt + 2 < nkt) ? 4 : 0);
    if (nwait == 8)      asm volatile("s_waitcnt vmcnt(8)" ::: "memory");
    else if (nwait == 4) asm volatile("s_waitcnt vmcnt(4)" ::: "memory");
    else                 asm volatile("s_waitcnt vmcnt(0)" ::: "memory");
    s16x8 bv[2][4];
    readB(bv);                                            // my B(t) -> regs
    asm volatile("s_waitcnt lgkmcnt(0)" ::: "memory");    // reads done
    if (kt + 1 < nkt) stageB(kt + 1);                     // overwrite my slice
    if (kt + 3 < nkt) {                                   // depth-3 prefetch
      const int s3 = (kt + 3) % 3;
      if (s3 == 0) issueA(kt + 3, ArA);
      else if (s3 == 1) issueA(kt + 3, ArB);
      else issueA(kt + 3, ArC);
    }
    if (kt + 1 < nkt) {                                   // write A(t+1) -> nxt
      const int s1 = (kt + 1) % 3;
      short* nxtA = ((kt + 1) & 1) ? lA1 : lA0;
      if (s1 == 0) writeA(ArA, nxtA);
      else if (s1 == 1) writeA(ArB, nxtA);
      else writeA(ArC, nxtA);
    }
    mfma((kt & 1) ? lA1 : lA0, bv);
    asm volatile("s_waitcnt lgkmcnt(0)" ::: "memory");    // A ds_writes done
    __builtin_amdgcn_s_barrier();                         // lA[(t+1)&1] visible
  }

  // ---- coalesced epilogue via LDS transpose (pad 264 = conflict-free)
  short* lC = (short*)smem;
#pragma unroll
  for (int ni = 0; ni < 4; ++ni) {
    const int col = wc * 64 + ni * 16 + (lane & 15);
    const float bvl = R.bias ? R.bias[col] : 0.0f;
#pragma unroll
    for (int mi = 0; mi < 4; ++mi) {
      const int rb = mi * 16 + ((lane >> 4) << 2);
#pragma unroll
      for (int q = 0; q < 4; ++q) {
        float vv = acc[mi][ni][q] + bvl;
        if (R.relu) vv = fmaxf(vv, 0.0f);
        lC[(rb + q) * 264 + col] = f2bf(vv);
      }
    }
  }
  __syncthreads();
#pragma unroll
  for (int p = 0; p < 8; ++p) {
    const int flat = p * 256 + tid;     // 64 rows x 32 chunks
    const int row = flat >> 5;
    const int ch = flat & 31;
    const int r = row0 + row;
    if (r < Nn)
      *(u16x8*)(R.C + (size_t)r * R.ldc + ch * 8) =
          *(const u16x8*)(lC + row * 264 + ch * 8);
  }
}

// ---------------- conv GEMM: all-gld_lds counted-vmcnt dbuf pipeline ----------
// BM=64, BN=256, 4 waves. LDS 80 KB. A row-padded past grid. 10 loads/step.
__global__ __launch_bounds__(256) void k_gemmC(
    const unsigned short* __restrict__ A, int lda, int K,
    const unsigned short* __restrict__ Wt, unsigned short* __restrict__ C,
    int ldc) {
  __shared__ char smem[81920];
  short* lA0 = (short*)smem;
  short* lA1 = (short*)(smem + 8192);
  short* lB0 = (short*)(smem + 16384);
  short* lB1 = (short*)(smem + 49152);
  const int tid = threadIdx.x;
  const int lane = tid & 63;
  const int wid = tid >> 6;
  const int wc = wid;
  const int row0 = blockIdx.x * 64;
  const int c16a = (lane & 7) ^ ((lane >> 3) & 7);

  f32x4 acc[4][4];
#pragma unroll
  for (int i = 0; i < 4; ++i)
#pragma unroll
    for (int j = 0; j < 4; ++j) acc[i][j] = (f32x4)0.0f;

  auto stage = [&](int kt) {
    short* a = (kt & 1) ? lA1 : lA0;
    short* b = (kt & 1) ? lB1 : lB0;
    const int k0 = kt * 64;
#pragma unroll
    for (int i = 0; i < 2; ++i) {
      const int iss = wid * 2 + i;
      const int row = row0 + iss * 8 + (lane >> 3);
      gld_lds16(A + (size_t)row * lda + k0 + c16a * 8, a + iss * 512);
    }
#pragma unroll
    for (int i = 0; i < 8; ++i) {
      const int iss = wid * 8 + i;
      const int col = iss * 8 + (lane >> 3);
      gld_lds16(Wt + (size_t)col * K + k0 + (lane & 7) * 8, b + iss * 512);
    }
  };
  auto mfma = [&](const short* lAb, const short* lBb) {
#pragma unroll
    for (int kk = 0; kk < 2; ++kk) {
      s16x8 af[4], bv[4];
#pragma unroll
      for (int mi = 0; mi < 4; ++mi) {
        int r = mi * 16 + (lane & 15);
        int byte = r * 128 + kk * 64 + (lane >> 4) * 16;
        byte ^= (r & 7) << 4;
        af[mi] = *(const s16x8*)((const char*)lAb + byte);
      }
#pragma unroll
      for (int ni = 0; ni < 4; ++ni) {
        int c = wc * 64 + ni * 16 + (lane & 15);
        int byte = c * 128 + kk * 64 + (lane >> 4) * 16;
        byte ^= (c & 7) << 4;
        bv[ni] = *(const s16x8*)((const char*)lBb + byte);
      }
#pragma unroll
      for (int mi = 0; mi < 4; ++mi)
#pragma unroll
        for (int ni = 0; ni < 4; ++ni)
          acc[mi][ni] = __builtin_amdgcn_mfma_f32_16x16x32_bf16(af[mi], bv[ni], acc[mi][ni], 0, 0, 0);
    }
  };

  const int nkt = K >> 6;
  stage(0);
  stage(1);
  for (int kt = 0; kt < nkt; ++kt) {
    short* curA = (kt & 1) ? lA1 : lA0;
    short* curB = (kt & 1) ? lB1 : lB0;
    if (kt + 1 < nkt) asm volatile("s_waitcnt vmcnt(10)" ::: "memory");
    else              asm volatile("s_waitcnt vmcnt(0)" ::: "memory");
    __builtin_amdgcn_s_barrier();
    mfma(curA, curB);
    __builtin_amdgcn_s_barrier();
    if (kt + 2 < nkt) stage(kt + 2);
  }

  short* lC = (short*)smem;
#pragma unroll
  for (int ni = 0; ni < 4; ++ni) {
    const int col = wc * 64 + ni * 16 + (lane & 15);
#pragma unroll
    for (int mi = 0; mi < 4; ++mi) {
      const int rb = mi * 16 + ((lane >> 4) << 2);
#pragma unroll
      for (int q = 0; q < 4; ++q)
        lC[(rb + q) * 264 + col] = f2bf(acc[mi][ni][q]);
    }
  }
  __syncthreads();
#pragma unroll
  for (int p = 0; p < 8; ++p) {
    const int flat = p * 256 + tid;
    const int row = flat >> 5;
    const int ch = flat & 31;
    const int r = row0 + row;
    if (r < Nn)
      *(u16x8*)(C + (size_t)r * ldc + ch * 8) =
          *(const u16x8*)(lC + row * 264 + ch * 8);
  }
}

// ---------------- cls GEMM: BM=256, BN=64, counted-vmcnt dbuf ----------------
__global__ __launch_bounds__(256) void k_gemmX(
    const unsigned short* __restrict__ A, int lda, int K,
    const unsigned short* __restrict__ Wt, unsigned short* __restrict__ C,
    int ldc, int ncols) {
  __shared__ char smem[81920];
  short* lA0 = (short*)smem;                // 32 KB
  short* lA1 = (short*)(smem + 32768);      // 32 KB
  short* lB0 = (short*)(smem + 65536);      // 8 KB
  short* lB1 = (short*)(smem + 73728);      // 8 KB
  const int tid = threadIdx.x;
  const int lane = tid & 63;
  const int wid = tid >> 6;
  const int wr = wid;            // waves split rows, share B cols 0..63
  const int row0 = blockIdx.x * 256;
  const int c16a = (lane & 7) ^ ((lane >> 3) & 7);

  f32x4 acc[4][4];
#pragma unroll
  for (int i = 0; i < 4; ++i)
#pragma unroll
    for (int j = 0; j < 4; ++j) acc[i][j] = (f32x4)0.0f;

  auto stage = [&](int kt) {
    short* a = (kt & 1) ? lA1 : lA0;
    short* b = (kt & 1) ? lB1 : lB0;
    const int k0 = kt * 64;
#pragma unroll
    for (int i = 0; i < 8; ++i) {
      const int iss = wid * 8 + i;
      const int row = row0 + iss * 8 + (lane >> 3);
      gld_lds16(A + (size_t)row * lda + k0 + c16a * 8, a + iss * 512);
    }
#pragma unroll
    for (int i = 0; i < 2; ++i) {
      const int iss = wid * 2 + i;
      const int col = iss * 8 + (lane >> 3);
      gld_lds16(Wt + (size_t)col * K + k0 + (lane & 7) * 8, b + iss * 512);
    }
  };
  auto mfma = [&](const short* a, const short* b) {
#pragma unroll
    for (int kk = 0; kk < 2; ++kk) {
      s16x8 af[4], bv[4];
#pragma unroll
      for (int mi = 0; mi < 4; ++mi) {
        int r = wr * 64 + mi * 16 + (lane & 15);
        int byte = r * 128 + kk * 64 + (lane >> 4) * 16;
        byte ^= (r & 7) << 4;
        af[mi] = *(const s16x8*)((const char*)a + byte);
      }
#pragma unroll
      for (int ni = 0; ni < 4; ++ni) {
        int c = ni * 16 + (lane & 15);
        int byte = c * 128 + kk * 64 + (lane >> 4) * 16;
        byte ^= (c & 7) << 4;
        bv[ni] = *(const s16x8*)((const char*)b + byte);
      }
#pragma unroll
      for (int mi = 0; mi < 4; ++mi)
#pragma unroll
        for (int ni = 0; ni < 4; ++ni)
          acc[mi][ni] = __builtin_amdgcn_mfma_f32_16x16x32_bf16(af[mi], bv[ni], acc[mi][ni], 0, 0, 0);
    }
  };

  const int nkt = K >> 6;
  stage(0);
  stage(1);
  for (int kt = 0; kt < nkt; ++kt) {
    short* curA = (kt & 1) ? lA1 : lA0;
    short* curB = (kt & 1) ? lB1 : lB0;
    if (kt + 1 < nkt) asm volatile("s_waitcnt vmcnt(10)" ::: "memory");
    else              asm volatile("s_waitcnt vmcnt(0)" ::: "memory");
    __builtin_amdgcn_s_barrier();
    mfma(curA, curB);
    __builtin_amdgcn_s_barrier();
    if (kt + 2 < nkt) stage(kt + 2);
  }

  short* lC = (short*)smem;   // 256 x 64 bf16, pad stride 72
#pragma unroll
  for (int ni = 0; ni < 4; ++ni) {
    const int col = ni * 16 + (lane & 15);
#pragma unroll
    for (int mi = 0; mi < 4; ++mi) {
      const int rb = wr * 64 + mi * 16 + ((lane >> 4) << 2);
#pragma unroll
      for (int q = 0; q < 4; ++q)
        lC[(rb + q) * 72 + col] = f2bf(acc[mi][ni][q]);
    }
  }
  __syncthreads();
#pragma unroll
  for (int p = 0; p < 8; ++p) {
    const int flat = p * 256 + tid;   // 256 rows x 8 chunks
    const int row = flat >> 3;
    const int ch = flat & 7;
    const int r = row0 + row;
    const int col = ch * 8;
    if (r < Nn && col < ncols)
      *(u16x8*)(C + (size_t)r * ldc + col) = *(const u16x8*)(lC + row * 72 + col);
  }
}

// ---------------- gather 256-dim: one wave per node, depth-4 pipeline ---------
__global__ __launch_bounds__(256) void k_gather(
    const unsigned short* __restrict__ m, const int* __restrict__ rowptr,
    const int* __restrict__ csrs, const float* __restrict__ csrn,
    const float* __restrict__ bias, unsigned short* __restrict__ outp,
    int ldc, int col_off) {
  const int wid = (blockIdx.x * 256 + threadIdx.x) >> 6;
  const int lane = threadIdx.x & 63;
  if (wid >= Nn) return;
  const int half = lane >> 5;
  const int sub = lane & 31;          // owns dims [sub*8, sub*8+8)
  const int e0 = rowptr[wid], e1 = rowptr[wid + 1];
  const unsigned short* mcol = m + sub * 8;
  float acc[8];
#pragma unroll
  for (int q = 0; q < 8; ++q) acc[q] = 0.f;

  for (int base = e0; base < e1; base += 64) {
    const int idx = base + lane;
    int s_ = 0;
    float w_ = 0.f;
    if (idx < e1) { s_ = csrs[idx]; w_ = csrn[idx]; }
    const int cn = min(64, e1 - base);
    const int npair = (cn + 1) >> 1;
    float w0, w1, w2, w3;
    u16x8 v0, v1, v2, v3;
    auto pick = [&](int p, float& w, u16x8& v) {
      if (p < npair) {           // wave-uniform branch
        const int j = 2 * p + half;
        const int ss = __shfl(s_, j);
        w = __shfl(w_, j);
        v = *(const u16x8*)(mcol + (size_t)ss * Hd);
      } else { w = 0.f; v = (u16x8)0; }
    };
    pick(0, w0, v0); pick(1, w1, v1); pick(2, w2, v2); pick(3, w3, v3);
    for (int p0 = 0; p0 < npair; p0 += 4) {
#pragma unroll
      for (int q = 0; q < 8; ++q) acc[q] += w0 * bf2f(v0[q]);
      pick(p0 + 4, w0, v0);
#pragma unroll
      for (int q = 0; q < 8; ++q) acc[q] += w1 * bf2f(v1[q]);
      pick(p0 + 5, w1, v1);
#pragma unroll
      for (int q = 0; q < 8; ++q) acc[q] += w2 * bf2f(v2[q]);
      pick(p0 + 6, w2, v2);
#pragma unroll
      for (int q = 0; q < 8; ++q) acc[q] += w3 * bf2f(v3[q]);
      pick(p0 + 7, w3, v3);
    }
  }

#pragma unroll
  for (int q = 0; q < 8; ++q) acc[q] += __shfl_xor(acc[q], 32);
  if (half == 0) {
    u16x8 o;
#pragma unroll
    for (int q = 0; q < 8; ++q) {
      float v = fmaxf(acc[q] + bias[sub * 8 + q], 0.f);
      o[q] = f2bf(v);
    }
    *(u16x8*)(outp + (size_t)wid * ldc + col_off + sub * 8) = o;
  }
}

// ---------------- cls gather + bias + log_softmax (40 dims) ----------------
__global__ __launch_bounds__(256) void k_gcls(
    const unsigned short* __restrict__ mc, const int* __restrict__ rowptr,
    const int* __restrict__ csrs, const float* __restrict__ csrn,
    const float* __restrict__ clsb, float* __restrict__ outp) {
  const int wid = (blockIdx.x * 256 + threadIdx.x) >> 6;
  const int lane = threadIdx.x & 63;
  if (wid >= Nn) return;
  const int half = lane >> 5;
  const int sub = lane & 31;
  const bool act = sub < 5;
  const int e0 = rowptr[wid], e1 = rowptr[wid + 1];
  float acc[8];
#pragma unroll
  for (int q = 0; q < 8; ++q) acc[q] = 0.f;

  for (int base = e0; base < e1; base += 64) {
    const int idx = base + lane;
    int s_ = 0;
    float w_ = 0.f;
    if (idx < e1) { s_ = csrs[idx]; w_ = csrn[idx]; }
    const int cn = min(64, e1 - base);
    const int npair = (cn + 1) >> 1;
    int sA = __shfl(s_, half);
    float wA = __shfl(w_, half);
    u16x8 vA = act ? *(const u16x8*)(mc + (size_t)sA * Cd + sub * 8) : (u16x8)0;
    for (int jj = 1; jj < npair; ++jj) {
      const int j = 2 * jj + half;
      const int sB = __shfl(s_, j);
      const float wB = __shfl(w_, j);
      const u16x8 vB = act ? *(const u16x8*)(mc + (size_t)sB * Cd + sub * 8) : (u16x8)0;
#pragma unroll
      for (int q = 0; q < 8; ++q) acc[q] += wA * bf2f(vA[q]);
      wA = wB; vA = vB;
    }
#pragma unroll
    for (int q = 0; q < 8; ++q) acc[q] += wA * bf2f(vA[q]);
  }

#pragma unroll
  for (int q = 0; q < 8; ++q) acc[q] += __shfl_xor(acc[q], 32);

  float l[8];
  float mx = -3.4e38f;
  if (act) {
#pragma unroll
    for (int q = 0; q < 8; ++q) {
      l[q] = acc[q] + clsb[sub * 8 + q];
      mx = fmaxf(mx, l[q]);
    }
  }
#pragma unroll
  for (int off = 1; off < 8; off <<= 1) mx = fmaxf(mx, __shfl_xor(mx, off));
  float se = 0.f;
  if (act) {
#pragma unroll
    for (int q = 0; q < 8; ++q) se += expf(l[q] - mx);
  }
#pragma unroll
  for (int off = 1; off < 8; off <<= 1) se += __shfl_xor(se, off);
  const float lse = mx + logf(se);
  if (half == 0 && act) {
    float* o1 = outp + (size_t)wid * Cd + sub * 8;
    float* o2 = o1 + (size_t)Nn * Cd;
#pragma unroll
    for (int q = 0; q < 8; ++q) {
      o1[q] = l[q] - lse;
      o2[q] = l[q];
    }
  }
}

}  // namespace

extern "C" void kernel_launch(void* const* d_in, const int* in_sizes, int n_in,
                              void* d_out, int out_size, void* d_ws, size_t ws_size,
                              hipStream_t stream) {
  (void)in_sizes; (void)n_in; (void)out_size; (void)ws_size;
  const float* x       = (const float*)d_in[0];
  const float* feature = (const float*)d_in[1];
  const int* src       = (const int*)d_in[2];
  const int* dst       = (const int*)d_in[3];
  const float* convW[3] = {(const float*)d_in[4], (const float*)d_in[6], (const float*)d_in[8]};
  const float* convB[3] = {(const float*)d_in[5], (const float*)d_in[7], (const float*)d_in[9]};
  const float* linW[3]  = {(const float*)d_in[10], (const float*)d_in[12], (const float*)d_in[14]};
  const float* linB[3]  = {(const float*)d_in[11], (const float*)d_in[13], (const float*)d_in[15]};
  const float* oweights = (const float*)d_in[16];
  const float* clsW     = (const float*)d_in[17];
  const float* clsB     = (const float*)d_in[18];
  float* out = (float*)d_out;

  char* wsp = (char*)d_ws;
  auto alloc = [&](size_t bytes) -> void* {
    void* p = wsp;
    wsp += (bytes + 255) & ~(size_t)255;
    return p;
  };
  int* cnt      = (int*)alloc((size_t)Nn * 4);
  int* cursor   = (int*)alloc((size_t)Nn * 4);
  int* rowptr   = (int*)alloc((size_t)(Nn + 1) * 4);
  float* dinv   = (float*)alloc((size_t)Nn * 4);
  int* partial  = (int*)alloc((size_t)NB * 4);
  int* poffs    = (int*)alloc((size_t)NB * 4);
  int* csrs     = (int*)alloc((size_t)(Ne + Nn) * 4);
  float* csrn   = (float*)alloc((size_t)(Ne + Nn) * 4);
  unsigned short* WtC0 = (unsigned short*)alloc((size_t)256 * 128 * 2);
  unsigned short* WtC1 = (unsigned short*)alloc((size_t)256 * 512 * 2);
  unsigned short* WtC2 = (unsigned short*)alloc((size_t)256 * 512 * 2);
  unsigned short* WtL0 = (unsigned short*)alloc((size_t)256 * 128 * 2);
  unsigned short* WtL1 = (unsigned short*)alloc((size_t)256 * 256 * 2);
  unsigned short* WtL2 = (unsigned short*)alloc((size_t)256 * 512 * 2);
  unsigned short* WtCl = (unsigned short*)alloc((size_t)64 * 512 * 2);
  unsigned short* mbuf = (unsigned short*)alloc((size_t)Nn * Hd * 2);
  unsigned short* mcls = (unsigned short*)alloc((size_t)Nn * Cd * 2);
  // combs padded +256 rows: direct A-loads of edge blocks read (and discard) pad
  unsigned short* comb0 = (unsigned short*)alloc((size_t)(Nn + 256) * 512 * 2);
  unsigned short* comb1 = (unsigned short*)alloc((size_t)(Nn + 256) * 512 * 2);
  unsigned short* comb2 = (unsigned short*)alloc((size_t)(Nn + 256) * 512 * 2);

  // ---- prep (weights + zero) and CSR build
  k_prep<<<(PREPTOT + 255) / 256, 256, 0, stream>>>(
      convW[0], convW[1], convW[2], linW[0], linW[1], linW[2], clsW, oweights,
      WtC0, WtC1, WtC2, WtL0, WtL1, WtL2, WtCl, cnt);
  k_count<<<(Ne + 255) / 256, 256, 0, stream>>>(dst, cnt);
  k_partial<<<NB, 256, 0, stream>>>(cnt, partial);
  k_scan_small<<<1, 256, 0, stream>>>(partial, poffs, rowptr);
  k_rowptr<<<NB, 256, 0, stream>>>(cnt, poffs, rowptr, cursor, dinv);
  k_fill<<<(Ne + Nn + 255) / 256, 256, 0, stream>>>(src, dst, dinv, cursor, csrs, csrn);

  const int GM = (Nn + 63) / 64;    // 782
  const int GC = (Nn + 255) / 256;  // 196
  const int GB = (Nn * 64) / 256;   // 12500, one wave per node

  // ---- all input-only GEMMs in ONE launch, roles interleaved in blockIdx.x
  GRole rConv0{x,                              WtC0, nullptr, mbuf,  128, Hd,  0};
  GRole rLin0 {feature,                        WtL0, linB[0], comb0, 128, 512, 1};
  GRole rLin1 {feature + (size_t)1 * Nn * Fd,  WtL1, linB[1], comb1, 256, 512, 1};
  GRole rLin2 {feature + (size_t)3 * Nn * Fd,  WtL2, linB[2], comb2, 512, 512, 1};
  k_gemm4<<<GM * 4, 256, 0, stream>>>(rConv0, rLin0, rLin1, rLin2);

  // ---- layer chain: gather(i) -> conv(i+1)
  k_gather<<<GB, 256, 0, stream>>>(mbuf, rowptr, csrs, csrn, convB[0], comb0, 512, 256);
  k_gemmC<<<GM, 256, 0, stream>>>(comb0, 512, 512, WtC1, mbuf, Hd);
  k_gather<<<GB, 256, 0, stream>>>(mbuf, rowptr, csrs, csrn, convB[1], comb1, 512, 256);
  k_gemmC<<<GM, 256, 0, stream>>>(comb1, 512, 512, WtC2, mbuf, Hd);
  k_gather<<<GB, 256, 0, stream>>>(mbuf, rowptr, csrs, csrn, convB[2], comb2, 512, 256);
  // ---- classifier
  k_gemmX<<<GC, 256, 0, stream>>>(comb2, 512, 512, WtCl, mcls, Cd, 40);
  k_gcls<<<GB, 256, 0, stream>>>(mcls, rowptr, csrs, csrn, clsB, out);
}

// Round 14
// 476.102 us; speedup vs baseline: 1.1213x; 1.1213x over previous
//
#include <hip/hip_runtime.h>

#define DEVI __device__ __forceinline__

namespace {

constexpr int Nn = 50000;   // nodes
constexpr int Ne = 800000;  // edges
constexpr int Fd = 128;     // feature dim
constexpr int Hd = 256;     // hidden
constexpr int Cd = 40;      // classes
constexpr int NB = (Nn + 255) / 256;  // 196 scan blocks

typedef __attribute__((ext_vector_type(8))) short s16x8;   // 8 bf16 MFMA frag
typedef __attribute__((ext_vector_type(8))) unsigned short u16x8;
typedef __attribute__((ext_vector_type(4))) float f32x4;
typedef __attribute__((ext_vector_type(4))) unsigned int u32x4;

DEVI unsigned short f2bf(float f) {
  unsigned int u = __builtin_bit_cast(unsigned int, f);
  u += 0x7fffu + ((u >> 16) & 1u);   // RNE
  return (unsigned short)(u >> 16);
}
DEVI float bf2f(unsigned short s) {
  return __builtin_bit_cast(float, ((unsigned int)s) << 16);
}
// 2x f32 -> packed bf16x2 (RNE), one VALU op (gfx950)
DEVI unsigned cvtpk(float lo, float hi) {
  unsigned r;
  asm("v_cvt_pk_bf16_f32 %0, %1, %2" : "=v"(r) : "v"(lo), "v"(hi));
  return r;
}

// Direct HBM->LDS 16B/lane load: M0 = wave-uniform LDS byte base,
// HW writes LDS at M0 + lane*16. gptr is per-lane. (validated R5)
DEVI void gld_lds16(const void* gptr, void* lds_base) {
  const unsigned m0v =
      (unsigned)__builtin_amdgcn_readfirstlane((unsigned)(uintptr_t)lds_base);
  asm volatile("s_mov_b32 m0, %0\n\t"
               "global_load_lds_dwordx4 %1, off"
               :: "s"(m0v), "v"(gptr) : "memory");
}

DEVI void wait_vm0_lgkm0() {
  asm volatile("s_waitcnt vmcnt(0) lgkmcnt(0)" ::: "memory");
}

// ---------------- fused prep: 7 weight transposes (PRE-SWIZZLED) + cnt zero ---
DEVI void wt_one(const float* __restrict__ W, unsigned short* __restrict__ Wt,
                 int idx, int K, int H, const float* __restrict__ ow) {
  int c = idx / K, k = idx - c * K;
  int kt = k >> 6, c16 = (k >> 3) & 7, j = k & 7;
  int ksrc = (kt << 6) | ((c16 ^ (c & 7)) << 3) | j;
  float v = (c < H) ? W[(size_t)ksrc * H + c] : 0.0f;
  if (ow) v *= ow[(ksrc >> 7) & 1];
  Wt[idx] = f2bf(v);
}

constexpr int WTO0 = 0;
constexpr int WTO1 = WTO0 + 256 * 128;  // convW0
constexpr int WTO2 = WTO1 + 256 * 512;  // convW1
constexpr int WTO3 = WTO2 + 256 * 512;  // convW2
constexpr int WTO4 = WTO3 + 256 * 128;  // linW0
constexpr int WTO5 = WTO4 + 256 * 256;  // linW1 (ow)
constexpr int WTO6 = WTO5 + 256 * 512;  // linW2 (ow)
constexpr int WTO7 = WTO6 + 64 * 512;   // clsW
constexpr int PREPTOT = WTO7 + Nn;

__global__ __launch_bounds__(256) void k_prep(
    const float* W0, const float* W1, const float* W2, const float* W3,
    const float* W4, const float* W5, const float* W6, const float* ow,
    unsigned short* T0, unsigned short* T1, unsigned short* T2, unsigned short* T3,
    unsigned short* T4, unsigned short* T5, unsigned short* T6, int* cnt) {
  int idx = blockIdx.x * 256 + threadIdx.x;
  if (idx >= PREPTOT) return;
  if (idx < WTO1)      wt_one(W0, T0, idx - WTO0, 128, 256, nullptr);
  else if (idx < WTO2) wt_one(W1, T1, idx - WTO1, 512, 256, nullptr);
  else if (idx < WTO3) wt_one(W2, T2, idx - WTO2, 512, 256, nullptr);
  else if (idx < WTO4) wt_one(W3, T3, idx - WTO3, 128, 256, nullptr);
  else if (idx < WTO5) wt_one(W4, T4, idx - WTO4, 256, 256, ow);
  else if (idx < WTO6) wt_one(W5, T5, idx - WTO5, 512, 256, ow);
  else if (idx < WTO7) wt_one(W6, T6, idx - WTO6, 512, 40, nullptr);
  else cnt[idx - WTO7] = 0;
}

// ---------------- CSR build ----------------
__global__ void k_count(const int* __restrict__ dst, int* __restrict__ cnt) {
  int e = blockIdx.x * 256 + threadIdx.x;
  if (e < Ne) atomicAdd(&cnt[dst[e]], 1);
}

__global__ __launch_bounds__(256) void k_partial(const int* __restrict__ cnt,
                                                 int* __restrict__ partial) {
  __shared__ int red[256];
  const int t = threadIdx.x;
  const int i = blockIdx.x * 256 + t;
  red[t] = (i < Nn) ? cnt[i] + 1 : 0;
  __syncthreads();
#pragma unroll
  for (int off = 128; off; off >>= 1) {
    if (t < off) red[t] += red[t + off];
    __syncthreads();
  }
  if (t == 0) partial[blockIdx.x] = red[0];
}

__global__ __launch_bounds__(256) void k_scan_small(const int* __restrict__ partial,
                                                    int* __restrict__ poffs,
                                                    int* __restrict__ rowptr) {
  __shared__ int s[256];
  const int t = threadIdx.x;
  const int v = (t < NB) ? partial[t] : 0;
  s[t] = v;
  __syncthreads();
#pragma unroll
  for (int off = 1; off < 256; off <<= 1) {
    int add = (t >= off) ? s[t - off] : 0;
    __syncthreads();
    s[t] += add;
    __syncthreads();
  }
  if (t < NB) poffs[t] = s[t] - v;        // exclusive
  if (t == NB - 1) rowptr[Nn] = s[t];     // total = Ne + Nn
}

__global__ __launch_bounds__(256) void k_rowptr(const int* __restrict__ cnt,
                                                const int* __restrict__ poffs,
                                                int* __restrict__ rowptr,
                                                int* __restrict__ cursor,
                                                float* __restrict__ dinv) {
  __shared__ int s[256];
  const int t = threadIdx.x;
  const int i = blockIdx.x * 256 + t;
  const int c = (i < Nn) ? cnt[i] + 1 : 0;
  s[t] = c;
  __syncthreads();
#pragma unroll
  for (int off = 1; off < 256; off <<= 1) {
    int add = (t >= off) ? s[t - off] : 0;
    __syncthreads();
    s[t] += add;
    __syncthreads();
  }
  if (i < Nn) {
    const int excl = s[t] - c + poffs[blockIdx.x];
    rowptr[i] = excl;
    cursor[i] = excl;
    dinv[i] = rsqrtf((float)c);
  }
}

__global__ void k_fill(const int* __restrict__ src, const int* __restrict__ dst,
                       const float* __restrict__ dinv, int* __restrict__ cursor,
                       int* __restrict__ csrs, float* __restrict__ csrn) {
  int e = blockIdx.x * 256 + threadIdx.x;
  if (e < Ne) {
    int s = src[e], d = dst[e];
    int pos = atomicAdd(&cursor[d], 1);
    csrs[pos] = s;
    csrn[pos] = dinv[s] * dinv[d];
  } else if (e < Ne + Nn) {
    int d = e - Ne;  // self loop
    int pos = atomicAdd(&cursor[d], 1);
    csrs[pos] = d;
    float v = dinv[d];
    csrn[pos] = v * v;
  }
}

// ---------------- fused MODE1 GEMM (4 roles): R10 schedule (best measured) ----
// BM=64, BN=256, 4 waves (wc=wid). LDS = A dbuf 2x8K + B single 32K = 48 KB.
// role = blockIdx.y. Per step: readB->regs | lgkm0 | issue {A(t+1), B(t+1)} |
// mfma(t) | writeA(t+1) | vm0+lgkm0 | barrier. Stage latency hides under mfma.
struct GRole {
  const float* A;
  const unsigned short* Wt;
  const float* bias;
  unsigned short* C;
  int K;
  int ldc;
  int relu;
};

__global__ __launch_bounds__(256) void k_gemm4(GRole R0, GRole R1, GRole R2, GRole R3) {
  const GRole R = (blockIdx.y == 0) ? R0 : (blockIdx.y == 1) ? R1
                  : (blockIdx.y == 2) ? R2 : R3;
  __shared__ char smem[49152];
  short* lA0 = (short*)smem;             // 8 KB
  short* lA1 = (short*)(smem + 8192);    // 8 KB
  short* lB  = (short*)(smem + 16384);   // 32 KB single, wave-private slices
  const int tid = threadIdx.x;
  const int lane = tid & 63;
  const int wid = tid >> 6;
  const int wc = wid;                 // wr = 0 (waves split cols)
  const int row0 = blockIdx.x * 64;
  const size_t NnF = (size_t)Nn * Fd;

  f32x4 acc[4][4];
#pragma unroll
  for (int i = 0; i < 4; ++i)
#pragma unroll
    for (int j = 0; j < 4; ++j) acc[i][j] = (f32x4)0.0f;

  auto issueA = [&](int kt, f32x4 (&A4)[2][2]) {
    const int k0 = kt * 64;
    const int c = k0 >> 7;
    const int f0 = k0 & 127;
#pragma unroll
    for (int i = 0; i < 2; ++i) {
      const int v = tid * 2 + i;
      const int row = v >> 3, c16 = v & 7;
      const int grow = row0 + row;
      const bool rv = grow < Nn;
      const float* p = R.A + (size_t)c * NnF + (size_t)grow * Fd + f0 + c16 * 8;
      A4[i][0] = rv ? *(const f32x4*)p : (f32x4)0.0f;
      A4[i][1] = rv ? *(const f32x4*)(p + 4) : (f32x4)0.0f;
    }
  };
  auto writeA = [&](f32x4 (&A4)[2][2], short* lAb) {
#pragma unroll
    for (int i = 0; i < 2; ++i) {
      const int v = tid * 2 + i;
      const int row = v >> 3, c16 = v & 7;
      u32x4 val;
      val.x = cvtpk(A4[i][0][0], A4[i][0][1]);
      val.y = cvtpk(A4[i][0][2], A4[i][0][3]);
      val.z = cvtpk(A4[i][1][0], A4[i][1][1]);
      val.w = cvtpk(A4[i][1][2], A4[i][1][3]);
      int byte = row * 128 + c16 * 16;
      byte ^= (row & 7) << 4;
      *(u32x4*)((char*)lAb + byte) = val;
    }
  };
  auto stageB = [&](int kt) {
    const int k0 = kt * 64;
#pragma unroll
    for (int i = 0; i < 8; ++i) {
      const int iss = wid * 8 + i;
      const int col = iss * 8 + (lane >> 3);
      gld_lds16(R.Wt + (size_t)col * R.K + k0 + (lane & 7) * 8, lB + iss * 512);
    }
  };
  auto readB = [&](s16x8 (&bv)[2][4]) {
#pragma unroll
    for (int kk = 0; kk < 2; ++kk)
#pragma unroll
      for (int ni = 0; ni < 4; ++ni) {
        int c = wc * 64 + ni * 16 + (lane & 15);
        int byte = c * 128 + kk * 64 + (lane >> 4) * 16;
        byte ^= (c & 7) << 4;
        bv[kk][ni] = *(const s16x8*)((const char*)lB + byte);
      }
  };
  auto mfma = [&](const short* lAb, s16x8 (&bv)[2][4]) {
#pragma unroll
    for (int kk = 0; kk < 2; ++kk) {
      s16x8 af[4];
#pragma unroll
      for (int mi = 0; mi < 4; ++mi) {
        int r = mi * 16 + (lane & 15);
        int byte = r * 128 + kk * 64 + (lane >> 4) * 16;
        byte ^= (r & 7) << 4;
        af[mi] = *(const s16x8*)((const char*)lAb + byte);
      }
#pragma unroll
      for (int mi = 0; mi < 4; ++mi)
#pragma unroll
        for (int ni = 0; ni < 4; ++ni)
          acc[mi][ni] = __builtin_amdgcn_mfma_f32_16x16x32_bf16(af[mi], bv[kk][ni], acc[mi][ni], 0, 0, 0);
    }
  };

  const int nkt = R.K >> 6;
  f32x4 Areg[2][2];
  issueA(0, Areg);
  stageB(0);
  writeA(Areg, lA0);       // reg-dep waits A(0); B(0) stays in flight
  wait_vm0_lgkm0();
  __builtin_amdgcn_s_barrier();
  for (int kt = 0; kt < nkt; ++kt) {
    short* curA = (kt & 1) ? lA1 : lA0;
    short* nxtA = (kt & 1) ? lA0 : lA1;
    s16x8 bv[2][4];
    readB(bv);   // my wave's B(t) slice -> regs
    asm volatile("s_waitcnt lgkmcnt(0)" ::: "memory");  // reads done before overwrite
    if (kt + 1 < nkt) { issueA(kt + 1, Areg); stageB(kt + 1); }
    mfma(curA, bv);
    if (kt + 1 < nkt) writeA(Areg, nxtA);
    wait_vm0_lgkm0();
    __builtin_amdgcn_s_barrier();
  }

  // ---- coalesced epilogue via LDS transpose (pad 264 = conflict-free)
  short* lC = (short*)smem;
#pragma unroll
  for (int ni = 0; ni < 4; ++ni) {
    const int col = wc * 64 + ni * 16 + (lane & 15);
    const float bvl = R.bias ? R.bias[col] : 0.0f;
#pragma unroll
    for (int mi = 0; mi < 4; ++mi) {
      const int rb = mi * 16 + ((lane >> 4) << 2);
#pragma unroll
      for (int q = 0; q < 4; ++q) {
        float vv = acc[mi][ni][q] + bvl;
        if (R.relu) vv = fmaxf(vv, 0.0f);
        lC[(rb + q) * 264 + col] = f2bf(vv);
      }
    }
  }
  __syncthreads();
#pragma unroll
  for (int p = 0; p < 8; ++p) {
    const int flat = p * 256 + tid;     // 64 rows x 32 chunks
    const int row = flat >> 5;
    const int ch = flat & 31;
    const int r = row0 + row;
    if (r < Nn)
      *(u16x8*)(R.C + (size_t)r * R.ldc + ch * 8) =
          *(const u16x8*)(lC + row * 264 + ch * 8);
  }
}

// ---------------- conv GEMM: all-gld_lds counted-vmcnt dbuf pipeline ----------
// BM=64, BN=256, 4 waves. LDS 80 KB. A row-padded past grid. 10 loads/step.
__global__ __launch_bounds__(256) void k_gemmC(
    const unsigned short* __restrict__ A, int lda, int K,
    const unsigned short* __restrict__ Wt, unsigned short* __restrict__ C,
    int ldc) {
  __shared__ char smem[81920];
  short* lA0 = (short*)smem;
  short* lA1 = (short*)(smem + 8192);
  short* lB0 = (short*)(smem + 16384);
  short* lB1 = (short*)(smem + 49152);
  const int tid = threadIdx.x;
  const int lane = tid & 63;
  const int wid = tid >> 6;
  const int wc = wid;
  const int row0 = blockIdx.x * 64;
  const int c16a = (lane & 7) ^ ((lane >> 3) & 7);

  f32x4 acc[4][4];
#pragma unroll
  for (int i = 0; i < 4; ++i)
#pragma unroll
    for (int j = 0; j < 4; ++j) acc[i][j] = (f32x4)0.0f;

  auto stage = [&](int kt) {
    short* a = (kt & 1) ? lA1 : lA0;
    short* b = (kt & 1) ? lB1 : lB0;
    const int k0 = kt * 64;
#pragma unroll
    for (int i = 0; i < 2; ++i) {
      const int iss = wid * 2 + i;
      const int row = row0 + iss * 8 + (lane >> 3);
      gld_lds16(A + (size_t)row * lda + k0 + c16a * 8, a + iss * 512);
    }
#pragma unroll
    for (int i = 0; i < 8; ++i) {
      const int iss = wid * 8 + i;
      const int col = iss * 8 + (lane >> 3);
      gld_lds16(Wt + (size_t)col * K + k0 + (lane & 7) * 8, b + iss * 512);
    }
  };
  auto mfma = [&](const short* lAb, const short* lBb) {
#pragma unroll
    for (int kk = 0; kk < 2; ++kk) {
      s16x8 af[4], bv[4];
#pragma unroll
      for (int mi = 0; mi < 4; ++mi) {
        int r = mi * 16 + (lane & 15);
        int byte = r * 128 + kk * 64 + (lane >> 4) * 16;
        byte ^= (r & 7) << 4;
        af[mi] = *(const s16x8*)((const char*)lAb + byte);
      }
#pragma unroll
      for (int ni = 0; ni < 4; ++ni) {
        int c = wc * 64 + ni * 16 + (lane & 15);
        int byte = c * 128 + kk * 64 + (lane >> 4) * 16;
        byte ^= (c & 7) << 4;
        bv[ni] = *(const s16x8*)((const char*)lBb + byte);
      }
#pragma unroll
      for (int mi = 0; mi < 4; ++mi)
#pragma unroll
        for (int ni = 0; ni < 4; ++ni)
          acc[mi][ni] = __builtin_amdgcn_mfma_f32_16x16x32_bf16(af[mi], bv[ni], acc[mi][ni], 0, 0, 0);
    }
  };

  const int nkt = K >> 6;
  stage(0);
  stage(1);
  for (int kt = 0; kt < nkt; ++kt) {
    short* curA = (kt & 1) ? lA1 : lA0;
    short* curB = (kt & 1) ? lB1 : lB0;
    if (kt + 1 < nkt) asm volatile("s_waitcnt vmcnt(10)" ::: "memory");
    else              asm volatile("s_waitcnt vmcnt(0)" ::: "memory");
    __builtin_amdgcn_s_barrier();
    mfma(curA, curB);
    __builtin_amdgcn_s_barrier();
    if (kt + 2 < nkt) stage(kt + 2);
  }

  short* lC = (short*)smem;
#pragma unroll
  for (int ni = 0; ni < 4; ++ni) {
    const int col = wc * 64 + ni * 16 + (lane & 15);
#pragma unroll
    for (int mi = 0; mi < 4; ++mi) {
      const int rb = mi * 16 + ((lane >> 4) << 2);
#pragma unroll
      for (int q = 0; q < 4; ++q)
        lC[(rb + q) * 264 + col] = f2bf(acc[mi][ni][q]);
    }
  }
  __syncthreads();
#pragma unroll
  for (int p = 0; p < 8; ++p) {
    const int flat = p * 256 + tid;
    const int row = flat >> 5;
    const int ch = flat & 31;
    const int r = row0 + row;
    if (r < Nn)
      *(u16x8*)(C + (size_t)r * ldc + ch * 8) =
          *(const u16x8*)(lC + row * 264 + ch * 8);
  }
}

// ---------------- cls GEMM: BM=256, BN=64, counted-vmcnt dbuf ----------------
__global__ __launch_bounds__(256) void k_gemmX(
    const unsigned short* __restrict__ A, int lda, int K,
    const unsigned short* __restrict__ Wt, unsigned short* __restrict__ C,
    int ldc, int ncols) {
  __shared__ char smem[81920];
  short* lA0 = (short*)smem;                // 32 KB
  short* lA1 = (short*)(smem + 32768);      // 32 KB
  short* lB0 = (short*)(smem + 65536);      // 8 KB
  short* lB1 = (short*)(smem + 73728);      // 8 KB
  const int tid = threadIdx.x;
  const int lane = tid & 63;
  const int wid = tid >> 6;
  const int wr = wid;            // waves split rows, share B cols 0..63
  const int row0 = blockIdx.x * 256;
  const int c16a = (lane & 7) ^ ((lane >> 3) & 7);

  f32x4 acc[4][4];
#pragma unroll
  for (int i = 0; i < 4; ++i)
#pragma unroll
    for (int j = 0; j < 4; ++j) acc[i][j] = (f32x4)0.0f;

  auto stage = [&](int kt) {
    short* a = (kt & 1) ? lA1 : lA0;
    short* b = (kt & 1) ? lB1 : lB0;
    const int k0 = kt * 64;
#pragma unroll
    for (int i = 0; i < 8; ++i) {
      const int iss = wid * 8 + i;
      const int row = row0 + iss * 8 + (lane >> 3);
      gld_lds16(A + (size_t)row * lda + k0 + c16a * 8, a + iss * 512);
    }
#pragma unroll
    for (int i = 0; i < 2; ++i) {
      const int iss = wid * 2 + i;
      const int col = iss * 8 + (lane >> 3);
      gld_lds16(Wt + (size_t)col * K + k0 + (lane & 7) * 8, b + iss * 512);
    }
  };
  auto mfma = [&](const short* a, const short* b) {
#pragma unroll
    for (int kk = 0; kk < 2; ++kk) {
      s16x8 af[4], bv[4];
#pragma unroll
      for (int mi = 0; mi < 4; ++mi) {
        int r = wr * 64 + mi * 16 + (lane & 15);
        int byte = r * 128 + kk * 64 + (lane >> 4) * 16;
        byte ^= (r & 7) << 4;
        af[mi] = *(const s16x8*)((const char*)a + byte);
      }
#pragma unroll
      for (int ni = 0; ni < 4; ++ni) {
        int c = ni * 16 + (lane & 15);
        int byte = c * 128 + kk * 64 + (lane >> 4) * 16;
        byte ^= (c & 7) << 4;
        bv[ni] = *(const s16x8*)((const char*)b + byte);
      }
#pragma unroll
      for (int mi = 0; mi < 4; ++mi)
#pragma unroll
        for (int ni = 0; ni < 4; ++ni)
          acc[mi][ni] = __builtin_amdgcn_mfma_f32_16x16x32_bf16(af[mi], bv[ni], acc[mi][ni], 0, 0, 0);
    }
  };

  const int nkt = K >> 6;
  stage(0);
  stage(1);
  for (int kt = 0; kt < nkt; ++kt) {
    short* curA = (kt & 1) ? lA1 : lA0;
    short* curB = (kt & 1) ? lB1 : lB0;
    if (kt + 1 < nkt) asm volatile("s_waitcnt vmcnt(10)" ::: "memory");
    else              asm volatile("s_waitcnt vmcnt(0)" ::: "memory");
    __builtin_amdgcn_s_barrier();
    mfma(curA, curB);
    __builtin_amdgcn_s_barrier();
    if (kt + 2 < nkt) stage(kt + 2);
  }

  short* lC = (short*)smem;   // 256 x 64 bf16, pad stride 72
#pragma unroll
  for (int ni = 0; ni < 4; ++ni) {
    const int col = ni * 16 + (lane & 15);
#pragma unroll
    for (int mi = 0; mi < 4; ++mi) {
      const int rb = wr * 64 + mi * 16 + ((lane >> 4) << 2);
#pragma unroll
      for (int q = 0; q < 4; ++q)
        lC[(rb + q) * 72 + col] = f2bf(acc[mi][ni][q]);
    }
  }
  __syncthreads();
#pragma unroll
  for (int p = 0; p < 8; ++p) {
    const int flat = p * 256 + tid;   // 256 rows x 8 chunks
    const int row = flat >> 3;
    const int ch = flat & 7;
    const int r = row0 + row;
    const int col = ch * 8;
    if (r < Nn && col < ncols)
      *(u16x8*)(C + (size_t)r * ldc + col) = *(const u16x8*)(lC + row * 72 + col);
  }
}

// ---------------- gather 256-dim: one wave per node, depth-4 pipeline ---------
__global__ __launch_bounds__(256) void k_gather(
    const unsigned short* __restrict__ m, const int* __restrict__ rowptr,
    const int* __restrict__ csrs, const float* __restrict__ csrn,
    const float* __restrict__ bias, unsigned short* __restrict__ outp,
    int ldc, int col_off) {
  const int wid = (blockIdx.x * 256 + threadIdx.x) >> 6;
  const int lane = threadIdx.x & 63;
  if (wid >= Nn) return;
  const int half = lane >> 5;
  const int sub = lane & 31;          // owns dims [sub*8, sub*8+8)
  const int e0 = rowptr[wid], e1 = rowptr[wid + 1];
  const unsigned short* mcol = m + sub * 8;
  float acc[8];
#pragma unroll
  for (int q = 0; q < 8; ++q) acc[q] = 0.f;

  for (int base = e0; base < e1; base += 64) {
    const int idx = base + lane;
    int s_ = 0;
    float w_ = 0.f;
    if (idx < e1) { s_ = csrs[idx]; w_ = csrn[idx]; }
    const int cn = min(64, e1 - base);
    const int npair = (cn + 1) >> 1;
    float w0, w1, w2, w3;
    u16x8 v0, v1, v2, v3;
    auto pick = [&](int p, float& w, u16x8& v) {
      if (p < npair) {           // wave-uniform branch
        const int j = 2 * p + half;
        const int ss = __shfl(s_, j);
        w = __shfl(w_, j);
        v = *(const u16x8*)(mcol + (size_t)ss * Hd);
      } else { w = 0.f; v = (u16x8)0; }
    };
    pick(0, w0, v0); pick(1, w1, v1); pick(2, w2, v2); pick(3, w3, v3);
    for (int p0 = 0; p0 < npair; p0 += 4) {
#pragma unroll
      for (int q = 0; q < 8; ++q) acc[q] += w0 * bf2f(v0[q]);
      pick(p0 + 4, w0, v0);
#pragma unroll
      for (int q = 0; q < 8; ++q) acc[q] += w1 * bf2f(v1[q]);
      pick(p0 + 5, w1, v1);
#pragma unroll
      for (int q = 0; q < 8; ++q) acc[q] += w2 * bf2f(v2[q]);
      pick(p0 + 6, w2, v2);
#pragma unroll
      for (int q = 0; q < 8; ++q) acc[q] += w3 * bf2f(v3[q]);
      pick(p0 + 7, w3, v3);
    }
  }

#pragma unroll
  for (int q = 0; q < 8; ++q) acc[q] += __shfl_xor(acc[q], 32);
  if (half == 0) {
    u16x8 o;
#pragma unroll
    for (int q = 0; q < 8; ++q) {
      float v = fmaxf(acc[q] + bias[sub * 8 + q], 0.f);
      o[q] = f2bf(v);
    }
    *(u16x8*)(outp + (size_t)wid * ldc + col_off + sub * 8) = o;
  }
}

// ---------------- cls gather + bias + log_softmax (40 dims) ----------------
__global__ __launch_bounds__(256) void k_gcls(
    const unsigned short* __restrict__ mc, const int* __restrict__ rowptr,
    const int* __restrict__ csrs, const float* __restrict__ csrn,
    const float* __restrict__ clsb, float* __restrict__ outp) {
  const int wid = (blockIdx.x * 256 + threadIdx.x) >> 6;
  const int lane = threadIdx.x & 63;
  if (wid >= Nn) return;
  const int half = lane >> 5;
  const int sub = lane & 31;
  const bool act = sub < 5;
  const int e0 = rowptr[wid], e1 = rowptr[wid + 1];
  float acc[8];
#pragma unroll
  for (int q = 0; q < 8; ++q) acc[q] = 0.f;

  for (int base = e0; base < e1; base += 64) {
    const int idx = base + lane;
    int s_ = 0;
    float w_ = 0.f;
    if (idx < e1) { s_ = csrs[idx]; w_ = csrn[idx]; }
    const int cn = min(64, e1 - base);
    const int npair = (cn + 1) >> 1;
    int sA = __shfl(s_, half);
    float wA = __shfl(w_, half);
    u16x8 vA = act ? *(const u16x8*)(mc + (size_t)sA * Cd + sub * 8) : (u16x8)0;
    for (int jj = 1; jj < npair; ++jj) {
      const int j = 2 * jj + half;
      const int sB = __shfl(s_, j);
      const float wB = __shfl(w_, j);
      const u16x8 vB = act ? *(const u16x8*)(mc + (size_t)sB * Cd + sub * 8) : (u16x8)0;
#pragma unroll
      for (int q = 0; q < 8; ++q) acc[q] += wA * bf2f(vA[q]);
      wA = wB; vA = vB;
    }
#pragma unroll
    for (int q = 0; q < 8; ++q) acc[q] += wA * bf2f(vA[q]);
  }

#pragma unroll
  for (int q = 0; q < 8; ++q) acc[q] += __shfl_xor(acc[q], 32);

  float l[8];
  float mx = -3.4e38f;
  if (act) {
#pragma unroll
    for (int q = 0; q < 8; ++q) {
      l[q] = acc[q] + clsb[sub * 8 + q];
      mx = fmaxf(mx, l[q]);
    }
  }
#pragma unroll
  for (int off = 1; off < 8; off <<= 1) mx = fmaxf(mx, __shfl_xor(mx, off));
  float se = 0.f;
  if (act) {
#pragma unroll
    for (int q = 0; q < 8; ++q) se += expf(l[q] - mx);
  }
#pragma unroll
  for (int off = 1; off < 8; off <<= 1) se += __shfl_xor(se, off);
  const float lse = mx + logf(se);
  if (half == 0 && act) {
    float* o1 = outp + (size_t)wid * Cd + sub * 8;
    float* o2 = o1 + (size_t)Nn * Cd;
#pragma unroll
    for (int q = 0; q < 8; ++q) {
      o1[q] = l[q] - lse;
      o2[q] = l[q];
    }
  }
}

}  // namespace

extern "C" void kernel_launch(void* const* d_in, const int* in_sizes, int n_in,
                              void* d_out, int out_size, void* d_ws, size_t ws_size,
                              hipStream_t stream) {
  (void)in_sizes; (void)n_in; (void)out_size; (void)ws_size;
  const float* x       = (const float*)d_in[0];
  const float* feature = (const float*)d_in[1];
  const int* src       = (const int*)d_in[2];
  const int* dst       = (const int*)d_in[3];
  const float* convW[3] = {(const float*)d_in[4], (const float*)d_in[6], (const float*)d_in[8]};
  const float* convB[3] = {(const float*)d_in[5], (const float*)d_in[7], (const float*)d_in[9]};
  const float* linW[3]  = {(const float*)d_in[10], (const float*)d_in[12], (const float*)d_in[14]};
  const float* linB[3]  = {(const float*)d_in[11], (const float*)d_in[13], (const float*)d_in[15]};
  const float* oweights = (const float*)d_in[16];
  const float* clsW     = (const float*)d_in[17];
  const float* clsB     = (const float*)d_in[18];
  float* out = (float*)d_out;

  char* wsp = (char*)d_ws;
  auto alloc = [&](size_t bytes) -> void* {
    void* p = wsp;
    wsp += (bytes + 255) & ~(size_t)255;
    return p;
  };
  int* cnt      = (int*)alloc((size_t)Nn * 4);
  int* cursor   = (int*)alloc((size_t)Nn * 4);
  int* rowptr   = (int*)alloc((size_t)(Nn + 1) * 4);
  float* dinv   = (float*)alloc((size_t)Nn * 4);
  int* partial  = (int*)alloc((size_t)NB * 4);
  int* poffs    = (int*)alloc((size_t)NB * 4);
  int* csrs     = (int*)alloc((size_t)(Ne + Nn) * 4);
  float* csrn   = (float*)alloc((size_t)(Ne + Nn) * 4);
  unsigned short* WtC0 = (unsigned short*)alloc((size_t)256 * 128 * 2);
  unsigned short* WtC1 = (unsigned short*)alloc((size_t)256 * 512 * 2);
  unsigned short* WtC2 = (unsigned short*)alloc((size_t)256 * 512 * 2);
  unsigned short* WtL0 = (unsigned short*)alloc((size_t)256 * 128 * 2);
  unsigned short* WtL1 = (unsigned short*)alloc((size_t)256 * 256 * 2);
  unsigned short* WtL2 = (unsigned short*)alloc((size_t)256 * 512 * 2);
  unsigned short* WtCl = (unsigned short*)alloc((size_t)64 * 512 * 2);
  unsigned short* mbuf = (unsigned short*)alloc((size_t)Nn * Hd * 2);
  unsigned short* mcls = (unsigned short*)alloc((size_t)Nn * Cd * 2);
  // combs padded +256 rows: direct A-loads of edge blocks read (and discard) pad
  unsigned short* comb0 = (unsigned short*)alloc((size_t)(Nn + 256) * 512 * 2);
  unsigned short* comb1 = (unsigned short*)alloc((size_t)(Nn + 256) * 512 * 2);
  unsigned short* comb2 = (unsigned short*)alloc((size_t)(Nn + 256) * 512 * 2);

  // ---- prep (weights + zero) and CSR build
  k_prep<<<(PREPTOT + 255) / 256, 256, 0, stream>>>(
      convW[0], convW[1], convW[2], linW[0], linW[1], linW[2], clsW, oweights,
      WtC0, WtC1, WtC2, WtL0, WtL1, WtL2, WtCl, cnt);
  k_count<<<(Ne + 255) / 256, 256, 0, stream>>>(dst, cnt);
  k_partial<<<NB, 256, 0, stream>>>(cnt, partial);
  k_scan_small<<<1, 256, 0, stream>>>(partial, poffs, rowptr);
  k_rowptr<<<NB, 256, 0, stream>>>(cnt, poffs, rowptr, cursor, dinv);
  k_fill<<<(Ne + Nn + 255) / 256, 256, 0, stream>>>(src, dst, dinv, cursor, csrs, csrn);

  const int GM = (Nn + 63) / 64;    // 782
  const int GC = (Nn + 255) / 256;  // 196
  const int GB = (Nn * 64) / 256;   // 12500, one wave per node

  // ---- all input-only GEMMs in ONE launch (conv0 + lin0 + lin1 + lin2)
  GRole rConv0{x,                              WtC0, nullptr, mbuf,  128, Hd,  0};
  GRole rLin0 {feature,                        WtL0, linB[0], comb0, 128, 512, 1};
  GRole rLin1 {feature + (size_t)1 * Nn * Fd,  WtL1, linB[1], comb1, 256, 512, 1};
  GRole rLin2 {feature + (size_t)3 * Nn * Fd,  WtL2, linB[2], comb2, 512, 512, 1};
  k_gemm4<<<dim3(GM, 4), 256, 0, stream>>>(rConv0, rLin0, rLin1, rLin2);

  // ---- layer chain: gather(i) -> conv(i+1)
  k_gather<<<GB, 256, 0, stream>>>(mbuf, rowptr, csrs, csrn, convB[0], comb0, 512, 256);
  k_gemmC<<<GM, 256, 0, stream>>>(comb0, 512, 512, WtC1, mbuf, Hd);
  k_gather<<<GB, 256, 0, stream>>>(mbuf, rowptr, csrs, csrn, convB[1], comb1, 512, 256);
  k_gemmC<<<GM, 256, 0, stream>>>(comb1, 512, 512, WtC2, mbuf, Hd);
  k_gather<<<GB, 256, 0, stream>>>(mbuf, rowptr, csrs, csrn, convB[2], comb2, 512, 256);
  // ---- classifier
  k_gemmX<<<GC, 256, 0, stream>>>(comb2, 512, 512, WtCl, mcls, Cd, 40);
  k_gcls<<<GB, 256, 0, stream>>>(mcls, rowptr, csrs, csrn, clsB, out);
}